// Round 15
// baseline (360.482 us; speedup 1.0000x reference)
//
#include <hip/hip_runtime.h>

typedef unsigned char u8;
typedef float f32x4 __attribute__((ext_vector_type(4)));
typedef float f4u __attribute__((ext_vector_type(4), aligned(4)));  // dword-aligned float4

#define P_OUT 29791      // 31^3
#define NCH   512

// ---- pack 4 fp32 -> 4 fp8 e4m3 (RNE, OCP) ----
__device__ __forceinline__ unsigned pk4_fp8(float a, float b, float c, float d) {
  int v = __builtin_amdgcn_cvt_pk_fp8_f32(a, b, 0, false);   // low word
  v = __builtin_amdgcn_cvt_pk_fp8_f32(c, d, v, true);        // high word
  return (unsigned)v;
}

// ---- w-prep: 512 rows, 16 rows/block, 32 blocks ----
__global__ void wprep_kernel(const float* __restrict__ w,
                             u8* __restrict__ wb, float* __restrict__ wsq) {
  const int tid = threadIdx.x;
  const int g = blockIdx.x * 16 + (tid >> 4);  // 0..511
  const int c = tid & 15;
  const float4* wr = (const float4*)(w + g * 128 + c * 8);
  float4 f0 = wr[0], f1 = wr[1];
  float s = f0.x*f0.x + f0.y*f0.y + f0.z*f0.z + f0.w*f0.w
          + f1.x*f1.x + f1.y*f1.y + f1.z*f1.z + f1.w*f1.w;
#pragma unroll
  for (int m = 1; m < 16; m <<= 1) s += __shfl_xor(s, m, 64);
  uint2 pk;
  pk.x = pk4_fp8(f0.x, f0.y, f0.z, f0.w);
  pk.y = pk4_fp8(f1.x, f1.y, f1.z, f1.w);
  *(uint2*)(wb + g * 128 + c * 8) = pk;
  if (c == 0) wsq[g] = s;
}

// async global->LDS, 16 B per lane, lands at ldsbase + lane*16
#define GLDS(g, l) __builtin_amdgcn_global_load_lds(                         \
    (const __attribute__((address_space(1))) unsigned int*)(g),              \
    (__attribute__((address_space(3))) unsigned int*)(l), 16, 0, 0)

// lgkm-only barrier: orders LDS ops across waves WITHOUT draining vmcnt,
// so global stores stay fire-and-forget (the r2 lesson). sched_barrier
// stops hipcc hoisting later LDS ops above it (guide rule #18).
#define LGKM_BAR() do {                                                      \
    asm volatile("s_waitcnt lgkmcnt(0)\n\ts_barrier" ::: "memory");          \
    __builtin_amdgcn_sched_barrier(0);                                       \
  } while (0)

// ---- DIAGNOSTIC build of the r14 kernel ----
// r14 verbatim, but the whole body runs TWICE (rep loop): identical values
// are recomputed and re-stored (idempotent, absmax 0). Purpose: the
// dispatch becomes ~200 us > the ~150 us harness fills, so rocprof's
// top-5 finally exposes THIS kernel's MfmaUtil/VALUBusy/FETCH/WRITE/
// LDS_CONFLICT. Per-pass traffic = reported / 2. Deliberate score
// sacrifice for one round; r14 remains the best production kernel.
__global__ __launch_bounds__(256, 2)
void gauss_fused_kernel(const float* __restrict__ x,
                        const u8* __restrict__ wb,
                        const float* __restrict__ wsq,
                        float* __restrict__ out) {
  __shared__ __align__(16) u8 SMEM[37888];
  u8* Ws = SMEM;                        // w tile [ch][k], 16 KB (phase 1-3)
  float* Xs = (float*)(SMEM + 16384);   // x slab [16c][328], 21 KB (ph 1-3)
  float* Ep = (float*)SMEM;             // epilogue [64][132] f32, 33.8 KB

  const int bid = blockIdx.x;
  const int tile = (bid & 7) * 496 + (bid >> 3);   // bijective XCD chunking
  const unsigned nb = (unsigned)tile / 992u;       // 4 batches
  const unsigned rem = (unsigned)tile - nb * 992u;
  const unsigned ct = rem / 248u;                  // 4 ch tiles
  const unsigned r2 = rem - ct * 248u;
  const unsigned d  = r2 >> 3;                     // 31 d values
  const unsigned hb = r2 & 7;                      // 8 h-blocks, fastest
  const int h0 = hb * 4;
  const int nh = (h0 + 4 <= 31) ? 4 : (31 - h0);   // 4 (hb<7) or 3 (hb=7)
  const int nrows = nh * 31;                       // 124 or 93
  const int c0 = ct * 128;
  const int tp0 = d * 961 + h0 * 31;               // tile's base p

  const int tid = threadIdx.x;
  const int wid = tid >> 6;
  const int lane = tid & 63;
  const int quad = lane >> 4;
  const int col = lane & 15;
  const int wch = wid & 1;   // wave ch-half
  const int wp = wid >> 1;   // wave p-half

  for (int rep = 0; rep < 2; ++rep) {

    // ---- stage W tile: 1024 swizzled chunks ----
#pragma unroll
    for (int t = 0; t < 4; ++t) {
      const int Lb = (wid * 4 + t) * 64;
      const int L = Lb + lane;
      const int row = L >> 3;
      const int jc = (L & 7) ^ (row & 7);
      GLDS(wb + (size_t)(c0 + row) * 128 + jc * 16, &Ws[Lb * 16]);
    }

    // ---- stage x slab [16c][82 chunks]: 80 data + 2 pad ----
#pragma unroll
    for (int t = 0; t < 6; ++t) {
      if (t < 5 || wid == 0) {
        const int Lb = t * 256 + wid * 64;
        const int L = Lb + lane;               // 0..1343
        unsigned c = (unsigned)L / 82u;
        if (c > 15u) c = 15u;
        unsigned rc = (unsigned)L - c * 82u;
        if (rc > 79u) rc = 79u;
        const unsigned kd = rc / 40u;
        const unsigned rr = rc - kd * 40u;
        const unsigned hq = rr >> 3;
        const int jc = (int)(rr & 7u);
        const int hg = h0 + (int)hq;
        const int hcl = (hg < 31) ? hg : 31;
        GLDS(x + (((size_t)(nb * 16 + c)) << 15) + (d + kd) * 1024 + hcl * 32 + jc * 4,
             &Xs[Lb * 4]);
      }
    }

    // ---- per-lane p-row decode (hides under GLDS flight) ----
    int rb[4];
    int xoff[4];
#pragma unroll
    for (int j = 0; j < 4; ++j) {
      rb[j] = wp * 64 + j * 16 + col;
      const unsigned rc = (unsigned)((rb[j] < nrows) ? rb[j] : (nrows - 1));
      const unsigned hh = rc / 31u;
      const unsigned wv = rc - hh * 31u;
      xoff[j] = (int)(hh * 32 + wv);
    }

    f32x4 acc[4][4];
#pragma unroll
    for (int i = 0; i < 4; ++i)
#pragma unroll
      for (int j = 0; j < 4; ++j) acc[i][j] = (f32x4){0.f, 0.f, 0.f, 0.f};

    float sq[4] = {0.f, 0.f, 0.f, 0.f};

    __syncthreads();   // drains GLDS (and, in rep 1, rep 0's stores -- noted)

    // ---- B pack + MFMA ----
    const int c16b = quad >> 1;
    const int hoff = (quad & 1) * 8;
#pragma unroll
    for (int ks = 0; ks < 4; ++ks) {
      long long a[4], b[4];
#pragma unroll
      for (int i = 0; i < 4; ++i) {
        const int rowA = wch * 64 + i * 16 + col;
        const int pa = (ks * 2 + c16b) ^ (rowA & 7);
        a[i] = *(const long long*)&Ws[rowA * 128 + pa * 16 + hoff];
      }
      const int cc = ks * 4 + quad;          // channel for this lane's k-chunk
      const float* xb = &Xs[cc * 328];       // [kd][hq][32] view, padded stride
#pragma unroll
      for (int j = 0; j < 4; ++j) {
        const float* pB = xb + xoff[j];
        // k-elem order = (kd,kh,kw): strides kd=160, kh=32, kw=1 floats
        const float v0 = pB[0],   v1 = pB[1],   v2 = pB[32],  v3 = pB[33];
        const float v4 = pB[160], v5 = pB[161], v6 = pB[192], v7 = pB[193];
        sq[j] += v0*v0 + v1*v1 + v2*v2 + v3*v3 + v4*v4 + v5*v5 + v6*v6 + v7*v7;
        const unsigned lo = pk4_fp8(v0, v1, v2, v3);
        const unsigned hi = pk4_fp8(v4, v5, v6, v7);
        b[j] = (long long)(((unsigned long long)hi << 32) | lo);
      }
#pragma unroll
      for (int i = 0; i < 4; ++i)
#pragma unroll
        for (int j = 0; j < 4; ++j)
          acc[i][j] = __builtin_amdgcn_mfma_f32_16x16x32_fp8_fp8(a[i], b[j],
                                                                 acc[i][j], 0, 0, 0);
    }
    // full ysq per row: reduce partials across the 4 quads
#pragma unroll
    for (int j = 0; j < 4; ++j) {
      sq[j] += __shfl_xor(sq[j], 16, 64);
      sq[j] += __shfl_xor(sq[j], 32, 64);
    }

    LGKM_BAR();   // all waves done with Ws/Xs -> Ep may overwrite SMEM

    // ---- transposed epilogue: 2 passes x {stage exp -> LDS, store rows} ----
    const int hw = lane >> 5;          // wave half (row selector)
    const int ll = lane & 31;          // lane within half
    const int nfull = (nrows == 124) ? 31 : 23;   // full-float4 lanes/strip
#pragma unroll
    for (int pa = 0; pa < 2; ++pa) {
      // stage: 32 ds_write_b32 per thread
#pragma unroll
      for (int ii = 0; ii < 2; ++ii) {
        const int i = pa * 2 + ii;
#pragma unroll
        for (int r = 0; r < 4; ++r) {
          const int ch2 = wch * 32 + ii * 16 + quad * 4 + r;
          const int chl = wch * 64 + pa * 32 + ii * 16 + quad * 4 + r;
          const float wsv = wsq[c0 + chl];
#pragma unroll
          for (int j = 0; j < 4; ++j)
            Ep[ch2 * 132 + rb[j]] = __expf(2.f * acc[i][j][r] - sq[j] - wsv);
        }
      }
      LGKM_BAR();   // Ep visible to all waves; stores NOT drained

      // store: 16 B/lane dwordx4, one instr = 2 x 496 B contiguous strips
#pragma unroll
      for (int rr = 0; rr < 8; ++rr) {
        const int ch2 = wid * 16 + rr * 2 + hw;
        const int chl = (ch2 >> 5) * 64 + pa * 32 + (ch2 & 31);
        float* ob = out + ((size_t)(nb * NCH + c0 + chl)) * P_OUT + tp0;
        if (ll < nfull) {
          const f4u v = *(const f4u*)&Ep[ch2 * 132 + 4 * ll];
          *(f4u*)(ob + 4 * ll) = v;
        } else if (ll == 23 && nrows == 93) {
          ob[92] = Ep[ch2 * 132 + 92];
        }
      }
      if (pa == 0) LGKM_BAR();   // all waves done reading Ep -> pass 2
    }

    if (rep == 0) LGKM_BAR();    // Ep ds_reads done -> rep 1 GLDS may land
  }
}

extern "C" void kernel_launch(void* const* d_in, const int* in_sizes, int n_in,
                              void* d_out, int out_size, void* d_ws, size_t ws_size,
                              hipStream_t stream) {
  const float* x = (const float*)d_in[0];
  const float* w = (const float*)d_in[1];
  float* out = (float*)d_out;
  char* ws = (char*)d_ws;
  // workspace: wb 512*128 fp8 = 65,536 B ; wsq 512*4 = 2,048 B
  u8* wb     = (u8*)ws;
  float* wsq = (float*)(ws + 65536);

  wprep_kernel<<<32, 256, 0, stream>>>(w, wb, wsq);
  gauss_fused_kernel<<<3968, 256, 0, stream>>>(x, wb, wsq, out);
}

// Round 16
// 248.002 us; speedup vs baseline: 1.4535x; 1.4535x over previous
//
#include <hip/hip_runtime.h>

typedef unsigned char u8;
typedef float f32x4 __attribute__((ext_vector_type(4)));
typedef float f4u __attribute__((ext_vector_type(4), aligned(4)));  // dword-aligned float4

#define P_OUT 29791      // 31^3
#define NCH   512

// ---- pack 4 fp32 -> 4 fp8 e4m3 (RNE, OCP) ----
__device__ __forceinline__ unsigned pk4_fp8(float a, float b, float c, float d) {
  int v = __builtin_amdgcn_cvt_pk_fp8_f32(a, b, 0, false);   // low word
  v = __builtin_amdgcn_cvt_pk_fp8_f32(c, d, v, true);        // high word
  return (unsigned)v;
}

// ---- w-prep: 512 rows, 16 rows/block, 32 blocks ----
__global__ void wprep_kernel(const float* __restrict__ w,
                             u8* __restrict__ wb, float* __restrict__ wsq) {
  const int tid = threadIdx.x;
  const int g = blockIdx.x * 16 + (tid >> 4);  // 0..511
  const int c = tid & 15;
  const float4* wr = (const float4*)(w + g * 128 + c * 8);
  float4 f0 = wr[0], f1 = wr[1];
  float s = f0.x*f0.x + f0.y*f0.y + f0.z*f0.z + f0.w*f0.w
          + f1.x*f1.x + f1.y*f1.y + f1.z*f1.z + f1.w*f1.w;
#pragma unroll
  for (int m = 1; m < 16; m <<= 1) s += __shfl_xor(s, m, 64);
  uint2 pk;
  pk.x = pk4_fp8(f0.x, f0.y, f0.z, f0.w);
  pk.y = pk4_fp8(f1.x, f1.y, f1.z, f1.w);
  *(uint2*)(wb + g * 128 + c * 8) = pk;
  if (c == 0) wsq[g] = s;
}

// async global->LDS, 16 B per lane, lands at ldsbase + lane*16
#define GLDS(g, l) __builtin_amdgcn_global_load_lds(                         \
    (const __attribute__((address_space(1))) unsigned int*)(g),              \
    (__attribute__((address_space(3))) unsigned int*)(l), 16, 0, 0)

// lgkm-only barrier: orders LDS ops across waves WITHOUT draining vmcnt.
#define LGKM_BAR() do {                                                      \
    asm volatile("s_waitcnt lgkmcnt(0)\n\ts_barrier" ::: "memory");          \
    __builtin_amdgcn_sched_barrier(0);                                       \
  } while (0)

// counted-vmcnt barrier (T4): waits until <=16 VMEM ops outstanding.
// vmcnt decrements IN ISSUE ORDER, so this forces any op with >=16
// younger ops (our Ws prefetch: always >=20 younger wsq-loads/stores)
// to completion while the NEWEST ~16 stores stay in flight.
#define VMC_BAR() do {                                                       \
    asm volatile("s_waitcnt vmcnt(16)\n\ts_barrier" ::: "memory");           \
    __builtin_amdgcn_sched_barrier(0);                                       \
  } while (0)

// ---- Fused unfold + GEMM, ct-loop + counted-vmcnt pipeline ----
// One block per (nb, d, hb): grid 992 = 8*124 (bijective XCD chunking).
// Xs staged ONCE, B packed ONCE (amortizes the two heaviest serial phases
// 4x vs r14's one-shot blocks); ct = 0..3 iterates the 4 ch-tiles with
// double-buffered Ws (GLDS prefetch of ct+2 issued after the post-MFMA
// lgkm barrier, completion enforced by VMC_BAR at iteration top --
// stores are NEVER drained to vmcnt(0), fixing r7's per-iter store drain).
// Pack (stride-328 padded Xs) + MFMA + transposed wide-store epilogue are
// r14-verbatim. LDS: Ws dbuf 32K + (Xs 21K | Ep 33.8K) = 65 KB, 2 blk/CU.
__global__ __launch_bounds__(256, 2)
void gauss_fused_kernel(const float* __restrict__ x,
                        const u8* __restrict__ wb,
                        const float* __restrict__ wsq,
                        float* __restrict__ out) {
  __shared__ __align__(16) u8 SMEM[66560];
  u8* Ws0 = SMEM;                       // w tile buf 0, 16 KB
  u8* Ws1 = SMEM + 16384;               // w tile buf 1, 16 KB
  float* Xs = (float*)(SMEM + 32768);   // x slab [16c][328], 21 KB (prologue)
  float* Ep = (float*)(SMEM + 32768);   // epilogue [64][132] f32 (ct loop)

  const int bid = blockIdx.x;
  const int tile = (bid & 7) * 124 + (bid >> 3);   // bijective XCD chunking
  const unsigned nb = (unsigned)tile / 248u;       // 4 batches
  const unsigned r2 = (unsigned)tile - nb * 248u;
  const unsigned d  = r2 >> 3;                     // 31 d values
  const unsigned hb = r2 & 7;                      // 8 h-blocks, fastest
  const int h0 = hb * 4;
  const int nh = (h0 + 4 <= 31) ? 4 : (31 - h0);   // 4 (hb<7) or 3 (hb=7)
  const int nrows = nh * 31;                       // 124 or 93
  const int tp0 = d * 961 + h0 * 31;               // tile's base p

  const int tid = threadIdx.x;
  const int wid = tid >> 6;
  const int lane = tid & 63;
  const int quad = lane >> 4;
  const int col = lane & 15;
  const int wch = wid & 1;   // wave ch-half
  const int wp = wid >> 1;   // wave p-half

  // ---- stage Ws0 (ct=0, channels 0-127): 1024 swizzled chunks ----
#pragma unroll
  for (int t = 0; t < 4; ++t) {
    const int Lb = (wid * 4 + t) * 64;
    const int L = Lb + lane;
    const int row = L >> 3;
    const int jc = (L & 7) ^ (row & 7);
    GLDS(wb + (size_t)row * 128 + jc * 16, &Ws0[Lb * 16]);
  }

  // ---- stage x slab [16c][82 chunks]: 80 data + 2 pad (r14 verbatim) ----
#pragma unroll
  for (int t = 0; t < 6; ++t) {
    if (t < 5 || wid == 0) {
      const int Lb = t * 256 + wid * 64;
      const int L = Lb + lane;               // 0..1343
      unsigned c = (unsigned)L / 82u;
      if (c > 15u) c = 15u;
      unsigned rc = (unsigned)L - c * 82u;
      if (rc > 79u) rc = 79u;
      const unsigned kd = rc / 40u;
      const unsigned rr = rc - kd * 40u;
      const unsigned hq = rr >> 3;
      const int jc = (int)(rr & 7u);
      const int hg = h0 + (int)hq;
      const int hcl = (hg < 31) ? hg : 31;
      GLDS(x + (((size_t)(nb * 16 + c)) << 15) + (d + kd) * 1024 + hcl * 32 + jc * 4,
           &Xs[Lb * 4]);
    }
  }

  // ---- per-lane p-row decode (hides under GLDS flight) ----
  int rb[4];
  int xoff[4];
#pragma unroll
  for (int j = 0; j < 4; ++j) {
    rb[j] = wp * 64 + j * 16 + col;
    const unsigned rc = (unsigned)((rb[j] < nrows) ? rb[j] : (nrows - 1));
    const unsigned hh = rc / 31u;
    const unsigned wv = rc - hh * 31u;
    xoff[j] = (int)(hh * 32 + wv);
  }

  __syncthreads();   // block start: drains Ws0 + Xs (no stores pending)

  // ---- prefetch Ws1 (ct=1, channels 128-255); flies under the pack ----
#pragma unroll
  for (int t = 0; t < 4; ++t) {
    const int Lb = (wid * 4 + t) * 64;
    const int L = Lb + lane;
    const int row = L >> 3;
    const int jc = (L & 7) ^ (row & 7);
    GLDS(wb + (size_t)(128 + row) * 128 + jc * 16, &Ws1[Lb * 16]);
  }

  // ---- pack B fragments ONCE into registers (r14-verbatim, stride 328) ----
  long long B[4][4];
  float sq[4] = {0.f, 0.f, 0.f, 0.f};
#pragma unroll
  for (int ks = 0; ks < 4; ++ks) {
    const int cc = ks * 4 + quad;          // channel for this lane's k-chunk
    const float* xb = &Xs[cc * 328];       // [kd][hq][32] view, padded stride
#pragma unroll
    for (int j = 0; j < 4; ++j) {
      const float* pB = xb + xoff[j];
      // k-elem order = (kd,kh,kw): strides kd=160, kh=32, kw=1 floats
      const float v0 = pB[0],   v1 = pB[1],   v2 = pB[32],  v3 = pB[33];
      const float v4 = pB[160], v5 = pB[161], v6 = pB[192], v7 = pB[193];
      sq[j] += v0*v0 + v1*v1 + v2*v2 + v3*v3 + v4*v4 + v5*v5 + v6*v6 + v7*v7;
      const unsigned lo = pk4_fp8(v0, v1, v2, v3);
      const unsigned hi = pk4_fp8(v4, v5, v6, v7);
      B[ks][j] = (long long)(((unsigned long long)hi << 32) | lo);
    }
  }
#pragma unroll
  for (int j = 0; j < 4; ++j) {
    sq[j] += __shfl_xor(sq[j], 16, 64);
    sq[j] += __shfl_xor(sq[j], 32, 64);
  }

  const int c16b = quad >> 1;
  const int hoff = (quad & 1) * 8;
  const int hw = lane >> 5;          // wave half (row selector)
  const int ll = lane & 31;          // lane within half
  const int nfull = (nrows == 124) ? 31 : 23;   // full-float4 lanes per strip

  // ---- ct loop: MFMA + epilogue per 128-ch tile, Ws double-buffered ----
#pragma unroll
  for (int ct = 0; ct < 4; ++ct) {
    if (ct > 0) VMC_BAR();           // Ws[ct&1] GLDS complete; stores fly on
    const u8* Wcur = (ct & 1) ? Ws1 : Ws0;

    f32x4 acc[4][4];
#pragma unroll
    for (int i = 0; i < 4; ++i)
#pragma unroll
      for (int j = 0; j < 4; ++j) acc[i][j] = (f32x4){0.f, 0.f, 0.f, 0.f};

#pragma unroll
    for (int ks = 0; ks < 4; ++ks) {
      long long a[4];
#pragma unroll
      for (int i = 0; i < 4; ++i) {
        const int rowA = wch * 64 + i * 16 + col;
        const int pa = (ks * 2 + c16b) ^ (rowA & 7);
        a[i] = *(const long long*)&Wcur[rowA * 128 + pa * 16 + hoff];
      }
#pragma unroll
      for (int i = 0; i < 4; ++i)
#pragma unroll
        for (int j = 0; j < 4; ++j)
          acc[i][j] = __builtin_amdgcn_mfma_f32_16x16x32_fp8_fp8(a[i], B[ks][j],
                                                                 acc[i][j], 0, 0, 0);
    }

    LGKM_BAR();   // all waves done reading Ws[ct&1] (+ Xs at ct=0) -> free

    // ---- refill the just-consumed buffer with ct+2 (flies under epilogue)
    if (ct < 2) {
      u8* Wn = (ct & 1) ? Ws1 : Ws0;
      const int cb = (ct + 2) * 128;
#pragma unroll
      for (int t = 0; t < 4; ++t) {
        const int Lb = (wid * 4 + t) * 64;
        const int L = Lb + lane;
        const int row = L >> 3;
        const int jc = (L & 7) ^ (row & 7);
        GLDS(wb + (size_t)(cb + row) * 128 + jc * 16, &Wn[Lb * 16]);
      }
    }

    // ---- transposed epilogue (r14-verbatim), c0 = ct*128 ----
    const int c0 = ct * 128;
#pragma unroll
    for (int pa = 0; pa < 2; ++pa) {
#pragma unroll
      for (int ii = 0; ii < 2; ++ii) {
        const int i = pa * 2 + ii;
#pragma unroll
        for (int r = 0; r < 4; ++r) {
          const int ch2 = wch * 32 + ii * 16 + quad * 4 + r;
          const int chl = wch * 64 + pa * 32 + ii * 16 + quad * 4 + r;
          const float wsv = wsq[c0 + chl];
#pragma unroll
          for (int j = 0; j < 4; ++j)
            Ep[ch2 * 132 + rb[j]] = __expf(2.f * acc[i][j][r] - sq[j] - wsv);
        }
      }
      LGKM_BAR();   // Ep visible to all waves; stores NOT drained

#pragma unroll
      for (int rr = 0; rr < 8; ++rr) {
        const int ch2 = wid * 16 + rr * 2 + hw;
        const int chl = (ch2 >> 5) * 64 + pa * 32 + (ch2 & 31);
        float* ob = out + ((size_t)(nb * NCH + c0 + chl)) * P_OUT + tp0;
        if (ll < nfull) {
          const f4u v = *(const f4u*)&Ep[ch2 * 132 + 4 * ll];  // 16B-aligned LDS
          *(f4u*)(ob + 4 * ll) = v;                            // dword-aligned ok
        } else if (ll == 23 && nrows == 93) {
          ob[92] = Ep[ch2 * 132 + 92];
        }
      }
      if (pa == 0) LGKM_BAR();   // Ep reads done -> pass 2 may overwrite
    }
  }
}

extern "C" void kernel_launch(void* const* d_in, const int* in_sizes, int n_in,
                              void* d_out, int out_size, void* d_ws, size_t ws_size,
                              hipStream_t stream) {
  const float* x = (const float*)d_in[0];
  const float* w = (const float*)d_in[1];
  float* out = (float*)d_out;
  char* ws = (char*)d_ws;
  // workspace: wb 512*128 fp8 = 65,536 B ; wsq 512*4 = 2,048 B
  u8* wb     = (u8*)ws;
  float* wsq = (float*)(ws + 65536);

  wprep_kernel<<<32, 256, 0, stream>>>(w, wb, wsq);
  gauss_fused_kernel<<<992, 256, 0, stream>>>(x, wb, wsq, out);
}